// Round 2
// baseline (978.386 us; speedup 1.0000x reference)
//
#include <hip/hip_runtime.h>

#define N_TOKENS 8192
#define IN_DIM   1024
#define OUT_DIM  1024
#define NE       8
#define HID      64

// ---------------- ws layout ----------------
// [0,   64)                : counts (8 int, memset to 0 each launch)
// [1024, 1024+8*8192*4)    : bucket_tok (int)
// [1024+262144, +262144)   : bucket_w  (float)

// =================== gating ===================
// 1 wave per token, 4 tokens per 256-thread block.
__global__ __launch_bounds__(256) void gating_kernel(
    const float* __restrict__ x, const float* __restrict__ Wg1, const float* __restrict__ bg1,
    const float* __restrict__ Wg2, const float* __restrict__ bg2,
    float* __restrict__ out_gw, float* __restrict__ out_idx,
    int* __restrict__ counts, int* __restrict__ bucket_tok, float* __restrict__ bucket_w)
{
    __shared__ float xs[4][IN_DIM];
    __shared__ float hs[4][HID];
    __shared__ float ss[4][NE];

    const int tid  = threadIdx.x;
    const int wave = tid >> 6;
    const int lane = tid & 63;
    const int token = blockIdx.x * 4 + wave;

    // stage this wave's x row into LDS (coalesced float4)
    const float4* xrow = (const float4*)(x + (size_t)token * IN_DIM);
    float4* xsv = (float4*)xs[wave];
#pragma unroll
    for (int j = 0; j < 4; ++j) xsv[lane + j * 64] = xrow[lane + j * 64];
    __syncthreads();

    // h[lane] = relu(dot(x_row, Wg1[lane]) + bg1[lane])
    float acc = bg1[lane];
    const float4* wrow = (const float4*)(Wg1 + (size_t)lane * IN_DIM);
    const float4* xr   = (const float4*)xs[wave];
    for (int k = 0; k < IN_DIM / 4; ++k) {
        float4 a = xr[k];
        float4 b = wrow[k];
        acc += a.x * b.x + a.y * b.y + a.z * b.z + a.w * b.w;
    }
    hs[wave][lane] = fmaxf(acc, 0.0f);
    __syncthreads();

    if (lane < NE) {
        float s = bg2[lane];
        const float* w2 = Wg2 + lane * HID;
#pragma unroll
        for (int j = 0; j < HID; ++j) s += hs[wave][j] * w2[j];
        ss[wave][lane] = s;
    }
    __syncthreads();

    if (lane == 0) {
        float sc[NE];
        float m = -1e30f;
#pragma unroll
        for (int e = 0; e < NE; ++e) { sc[e] = ss[wave][e]; m = fmaxf(m, sc[e]); }
        float sum = 0.0f;
#pragma unroll
        for (int e = 0; e < NE; ++e) { sc[e] = expf(sc[e] - m); sum += sc[e]; }
        const float inv = 1.0f / sum;
#pragma unroll
        for (int e = 0; e < NE; ++e) { sc[e] *= inv; out_gw[(size_t)token * NE + e] = sc[e]; }

        // top-2, first-index wins on ties (matches lax.top_k)
        int i1 = 0; float v1 = sc[0];
#pragma unroll
        for (int e = 1; e < NE; ++e) if (sc[e] > v1) { v1 = sc[e]; i1 = e; }
        int i2 = -1; float v2 = -1e30f;
#pragma unroll
        for (int e = 0; e < NE; ++e) {
            if (e == i1) continue;
            if (i2 < 0 || sc[e] > v2) { v2 = sc[e]; i2 = e; }
        }
        out_idx[(size_t)token * 2 + 0] = (float)i1;
        out_idx[(size_t)token * 2 + 1] = (float)i2;

        int p1 = atomicAdd(&counts[i1], 1);
        bucket_tok[i1 * N_TOKENS + p1] = token;
        bucket_w  [i1 * N_TOKENS + p1] = v1;
        int p2 = atomicAdd(&counts[i2], 1);
        bucket_tok[i2 * N_TOKENS + p2] = token;
        bucket_w  [i2 * N_TOKENS + p2] = v2;
    }
}

// =================== grouped expert GEMM ===================
// 128x128 tile, BK=16, 256 threads, 8x8 acc/thread (interleaved 4+4 halves).
#define BM 128
#define BN 128
#define BK 16

__global__ __launch_bounds__(256) void expert_gemm(
    const float* __restrict__ x, const float* __restrict__ We, const float* __restrict__ be,
    const int* __restrict__ counts, const int* __restrict__ bucket_tok,
    const float* __restrict__ bucket_w, float* __restrict__ out)
{
    const int e  = blockIdx.z;
    const int tt = blockIdx.y;
    const int ot = blockIdx.x;
    const int cnt = counts[e];
    if (tt * BM >= cnt) return;

    __shared__ float Xs[BK][BM + 4];   // K-major: fragment reads are float4
    __shared__ float Ws[BK][BM + 4];
    __shared__ int   toks[BM];
    __shared__ float wts[BM];

    const int tid = threadIdx.x;

    // stage bucket metadata (128 entries, threads 0..127)
    if (tid < BM) {
        int idx = tt * BM + tid;
        if (idx < cnt) {
            toks[tid] = bucket_tok[e * N_TOKENS + idx];
            wts [tid] = bucket_w [e * N_TOKENS + idx];
        } else {
            toks[tid] = -1;
            wts [tid] = 0.0f;
        }
    }
    __syncthreads();

    // staging: 2 threads per row, each loads 8 floats (2 float4) of X and W
    const int r = tid >> 1;            // 0..127
    const int h = tid & 1;             // half of the 16-float k-slab
    const int tok_r = toks[r];
    const float* xbase = x + (size_t)(tok_r < 0 ? 0 : tok_r) * IN_DIM + h * 8;
    const float* wbase = We + ((size_t)e * OUT_DIM + ot * BN + r) * IN_DIM + h * 8;

    // compute mapping: 16x16 threads, each owns rows {ty*4+i, 64+ty*4+i},
    // cols {tx*4+j, 64+tx*4+j}  (interleaved halves -> 2-way-free LDS banks)
    const int ty = tid >> 4;
    const int tx = tid & 15;

    float acc[8][8] = {};

    for (int k0 = 0; k0 < IN_DIM; k0 += BK) {
        float4 xa0 = *(const float4*)(xbase + k0);
        float4 xa1 = *(const float4*)(xbase + k0 + 4);
        float4 wa0 = *(const float4*)(wbase + k0);
        float4 wa1 = *(const float4*)(wbase + k0 + 4);

        __syncthreads();   // previous iteration's fragment reads complete
        Xs[h * 8 + 0][r] = xa0.x; Xs[h * 8 + 1][r] = xa0.y;
        Xs[h * 8 + 2][r] = xa0.z; Xs[h * 8 + 3][r] = xa0.w;
        Xs[h * 8 + 4][r] = xa1.x; Xs[h * 8 + 5][r] = xa1.y;
        Xs[h * 8 + 6][r] = xa1.z; Xs[h * 8 + 7][r] = xa1.w;
        Ws[h * 8 + 0][r] = wa0.x; Ws[h * 8 + 1][r] = wa0.y;
        Ws[h * 8 + 2][r] = wa0.z; Ws[h * 8 + 3][r] = wa0.w;
        Ws[h * 8 + 4][r] = wa1.x; Ws[h * 8 + 5][r] = wa1.y;
        Ws[h * 8 + 6][r] = wa1.z; Ws[h * 8 + 7][r] = wa1.w;
        __syncthreads();

#pragma unroll
        for (int kk = 0; kk < BK; ++kk) {
            float4 a0 = *(const float4*)&Xs[kk][ty * 4];
            float4 a1 = *(const float4*)&Xs[kk][64 + ty * 4];
            float4 b0 = *(const float4*)&Ws[kk][tx * 4];
            float4 b1 = *(const float4*)&Ws[kk][64 + tx * 4];
            float av[8] = {a0.x, a0.y, a0.z, a0.w, a1.x, a1.y, a1.z, a1.w};
            float bv[8] = {b0.x, b0.y, b0.z, b0.w, b1.x, b1.y, b1.z, b1.w};
#pragma unroll
            for (int i = 0; i < 8; ++i)
#pragma unroll
                for (int j = 0; j < 8; ++j)
                    acc[i][j] += av[i] * bv[j];
        }
    }

    // epilogue: out[tok] += w * (acc + bias)
    const float* berow = be + (size_t)e * OUT_DIM + ot * BN;
    float bias[8];
#pragma unroll
    for (int j = 0; j < 8; ++j)
        bias[j] = berow[(j >> 2) * 64 + tx * 4 + (j & 3)];

#pragma unroll
    for (int i = 0; i < 8; ++i) {
        const int ri  = (i >> 2) * 64 + ty * 4 + (i & 3);
        const int tok = toks[ri];
        if (tok < 0) continue;
        const float w = wts[ri];
        float* orow = out + (size_t)tok * OUT_DIM + ot * BN;
#pragma unroll
        for (int j = 0; j < 8; ++j) {
            atomicAdd(&orow[(j >> 2) * 64 + tx * 4 + (j & 3)], w * (acc[i][j] + bias[j]));
        }
    }
}

extern "C" void kernel_launch(void* const* d_in, const int* in_sizes, int n_in,
                              void* d_out, int out_size, void* d_ws, size_t ws_size,
                              hipStream_t stream) {
    const float* x   = (const float*)d_in[0];
    const float* We  = (const float*)d_in[1];
    const float* be  = (const float*)d_in[2];
    const float* Wg1 = (const float*)d_in[3];
    const float* bg1 = (const float*)d_in[4];
    const float* Wg2 = (const float*)d_in[5];
    const float* bg2 = (const float*)d_in[6];

    float* out     = (float*)d_out;
    float* out_gw  = out + (size_t)N_TOKENS * OUT_DIM;          // [N, 8]
    float* out_idx = out_gw + (size_t)N_TOKENS * NE;            // [N, 2] (as float)

    char* ws = (char*)d_ws;
    int*   counts     = (int*)ws;
    int*   bucket_tok = (int*)(ws + 1024);
    float* bucket_w   = (float*)(ws + 1024 + (size_t)NE * N_TOKENS * 4);

    hipMemsetAsync(counts, 0, 64, stream);
    hipMemsetAsync(out, 0, (size_t)N_TOKENS * OUT_DIM * sizeof(float), stream);

    gating_kernel<<<N_TOKENS / 4, 256, 0, stream>>>(
        x, Wg1, bg1, Wg2, bg2, out_gw, out_idx, counts, bucket_tok, bucket_w);

    dim3 grid(OUT_DIM / BN, N_TOKENS / BM, NE);
    expert_gemm<<<grid, 256, 0, stream>>>(
        x, We, be, counts, bucket_tok, bucket_w, out);
}

// Round 5
// 258.575 us; speedup vs baseline: 3.7838x; 3.7838x over previous
//
#include <hip/hip_runtime.h>
#include <stdint.h>

#define N_TOKENS 8192
#define IN_DIM   1024
#define OUT_DIM  1024
#define NE       8
#define HID      64

typedef __attribute__((ext_vector_type(8))) short bf16x8;   // 8 bf16 = 4 VGPR
typedef __attribute__((ext_vector_type(4))) float f32x4;

// ---------------- helpers ----------------
__device__ __forceinline__ unsigned short f2bf(float f) {   // RN-even fp32->bf16
    unsigned int b = __float_as_uint(f);
    b += 0x7fffu + ((b >> 16) & 1u);
    return (unsigned short)(b >> 16);
}

__device__ __forceinline__ void gl16(const unsigned short* g, unsigned short* l) {
    // async global->LDS, 16B per lane; LDS dest = wave-uniform base + lane*16
    __builtin_amdgcn_global_load_lds(
        (const __attribute__((address_space(1))) unsigned int*)g,
        (__attribute__((address_space(3))) unsigned int*)l,
        16, 0, 0);
}

// =================== fp32 -> bf16 ===================
__global__ __launch_bounds__(256) void conv_bf16(
    const float* __restrict__ src, unsigned short* __restrict__ dst, int n4)
{
    int i = blockIdx.x * 256 + threadIdx.x;
    const int stride = gridDim.x * 256;
    for (; i < n4; i += stride) {
        float4 v = ((const float4*)src)[i];
        ushort4 h;
        h.x = f2bf(v.x); h.y = f2bf(v.y); h.z = f2bf(v.z); h.w = f2bf(v.w);
        ((ushort4*)dst)[i] = h;
    }
}

// =================== gating ===================
// 64 tokens per block, 256 threads. Tiled fp32 GEMM for H = relu(X*Wg1^T+b),
// then per-token scores/softmax/top2 on wave 0, wave-aggregated bucket scatter.
// Bucket entries pack token*2+rank so the expert GEMM can write rank-addressed slots.
__global__ __launch_bounds__(256) void gating_kernel(
    const float* __restrict__ x, const float* __restrict__ Wg1, const float* __restrict__ bg1,
    const float* __restrict__ Wg2, const float* __restrict__ bg2,
    float* __restrict__ out_gw, float* __restrict__ out_idx,
    int* __restrict__ counts, int* __restrict__ bucket_tok, float* __restrict__ bucket_w)
{
    __shared__ float Xs[32][68];     // [k][token]
    __shared__ float Gs[32][68];     // [k][hid]
    __shared__ float Hs[64][65];     // [token][hid]
    __shared__ float W2s[NE][HID];
    __shared__ float b2s[NE];

    const int tid = threadIdx.x;
    const int t0  = blockIdx.x * 64;

    for (int i = tid; i < NE * HID; i += 256) W2s[i >> 6][i & 63] = Wg2[i];
    if (tid < NE) b2s[tid] = bg2[tid];

    const int ty = tid >> 4, tx = tid & 15;
    float acc[4][4] = {};

    const int sr  = tid >> 2;        // 0..63: token row (X) / hidden row (Wg1)
    const int skq = tid & 3;         // k-quad
    const float* xsrc = x   + (size_t)(t0 + sr) * IN_DIM + skq * 8;
    const float* gsrc = Wg1 + (size_t)sr        * IN_DIM + skq * 8;

    for (int k0 = 0; k0 < IN_DIM; k0 += 32) {
        __syncthreads();
        float4 v0 = *(const float4*)(xsrc + k0);
        float4 v1 = *(const float4*)(xsrc + k0 + 4);
        float4 w0 = *(const float4*)(gsrc + k0);
        float4 w1 = *(const float4*)(gsrc + k0 + 4);
        Xs[skq*8+0][sr]=v0.x; Xs[skq*8+1][sr]=v0.y; Xs[skq*8+2][sr]=v0.z; Xs[skq*8+3][sr]=v0.w;
        Xs[skq*8+4][sr]=v1.x; Xs[skq*8+5][sr]=v1.y; Xs[skq*8+6][sr]=v1.z; Xs[skq*8+7][sr]=v1.w;
        Gs[skq*8+0][sr]=w0.x; Gs[skq*8+1][sr]=w0.y; Gs[skq*8+2][sr]=w0.z; Gs[skq*8+3][sr]=w0.w;
        Gs[skq*8+4][sr]=w1.x; Gs[skq*8+5][sr]=w1.y; Gs[skq*8+6][sr]=w1.z; Gs[skq*8+7][sr]=w1.w;
        __syncthreads();
#pragma unroll
        for (int kk = 0; kk < 32; ++kk) {
            float4 a = *(const float4*)&Xs[kk][ty * 4];
            float4 b = *(const float4*)&Gs[kk][tx * 4];
            acc[0][0] += a.x*b.x; acc[0][1] += a.x*b.y; acc[0][2] += a.x*b.z; acc[0][3] += a.x*b.w;
            acc[1][0] += a.y*b.x; acc[1][1] += a.y*b.y; acc[1][2] += a.y*b.z; acc[1][3] += a.y*b.w;
            acc[2][0] += a.z*b.x; acc[2][1] += a.z*b.y; acc[2][2] += a.z*b.z; acc[2][3] += a.z*b.w;
            acc[3][0] += a.w*b.x; acc[3][1] += a.w*b.y; acc[3][2] += a.w*b.z; acc[3][3] += a.w*b.w;
        }
    }

    float bg[4];
#pragma unroll
    for (int j = 0; j < 4; ++j) bg[j] = bg1[tx * 4 + j];
#pragma unroll
    for (int i = 0; i < 4; ++i)
#pragma unroll
        for (int j = 0; j < 4; ++j)
            Hs[ty * 4 + i][tx * 4 + j] = fmaxf(acc[i][j] + bg[j], 0.0f);
    __syncthreads();

    if (tid < 64) {                  // wave 0 only
        const int token = t0 + tid;
        float sc[NE];
#pragma unroll
        for (int e2 = 0; e2 < NE; ++e2) {
            float s = b2s[e2];
#pragma unroll
            for (int j = 0; j < HID; ++j) s += Hs[tid][j] * W2s[e2][j];
            sc[e2] = s;
        }
        float m = sc[0];
#pragma unroll
        for (int e2 = 1; e2 < NE; ++e2) m = fmaxf(m, sc[e2]);
        float sum = 0.0f;
#pragma unroll
        for (int e2 = 0; e2 < NE; ++e2) { sc[e2] = expf(sc[e2] - m); sum += sc[e2]; }
        const float inv = 1.0f / sum;
#pragma unroll
        for (int e2 = 0; e2 < NE; ++e2) { sc[e2] *= inv; out_gw[(size_t)token * NE + e2] = sc[e2]; }

        int i1 = 0; float v1 = sc[0];
#pragma unroll
        for (int e2 = 1; e2 < NE; ++e2) if (sc[e2] > v1) { v1 = sc[e2]; i1 = e2; }
        int i2 = -1; float v2 = -1e30f;
#pragma unroll
        for (int e2 = 0; e2 < NE; ++e2) {
            if (e2 == i1) continue;
            if (i2 < 0 || sc[e2] > v2) { v2 = sc[e2]; i2 = e2; }
        }
        out_idx[(size_t)token * 2 + 0] = (float)i1;
        out_idx[(size_t)token * 2 + 1] = (float)i2;

        // wave-aggregated bucket scatter: 16 atomics/block on 64B-strided counters
        const unsigned long long lmask = (1ull << tid) - 1ull;
#pragma unroll
        for (int e2 = 0; e2 < NE; ++e2) {
            unsigned long long m1 = __ballot(i1 == e2);
            unsigned long long m2 = __ballot(i2 == e2);
            int c1 = __popcll(m1), c2 = __popcll(m2);
            int base = 0;
            if (tid == 0 && (c1 + c2) > 0) base = atomicAdd(&counts[e2 * 16], c1 + c2);
            base = __shfl(base, 0);
            if (i1 == e2) {
                int pos = base + __popcll(m1 & lmask);
                bucket_tok[e2 * N_TOKENS + pos] = token * 2 + 0;   // rank 0
                bucket_w  [e2 * N_TOKENS + pos] = v1;
            }
            if (i2 == e2) {
                int pos = base + c1 + __popcll(m2 & lmask);
                bucket_tok[e2 * N_TOKENS + pos] = token * 2 + 1;   // rank 1
                bucket_w  [e2 * N_TOKENS + pos] = v2;
            }
        }
    }
}

// =================== grouped expert GEMM (bf16 MFMA) ===================
// 128x128 tile, 4 waves (2x2), each wave 64x64 = 4x4 frags of 16x16x32.
// Writes w*(acc+bias) to tmp[slot][:] with plain stores (slot = token*2+rank).
#define BM 128
#define KS 32   // bf16 k per stage

__global__ __launch_bounds__(256) void expert_gemm(
    const unsigned short* __restrict__ xh, const unsigned short* __restrict__ wh,
    const float* __restrict__ be, const int* __restrict__ counts,
    const int* __restrict__ bucket_tok, const float* __restrict__ bucket_w,
    float* __restrict__ tmp)
{
    const int e  = blockIdx.z;
    const int tt = blockIdx.y;
    const int ot = blockIdx.x;
    const int cnt = counts[e * 16];
    if (tt * BM >= cnt) return;

    __shared__ unsigned short Xh[BM * KS], Wh[BM * KS];   // 8KB each
    __shared__ int   slt[BM];
    __shared__ float wts[BM];

    const int tid  = threadIdx.x;
    const int wv   = tid >> 6;
    const int lane = tid & 63;

    if (tid < BM) {
        int idx = tt * BM + tid;
        slt[tid] = (idx < cnt) ? bucket_tok[e * N_TOKENS + idx] : -1;   // -1 = pad
        wts[tid] = (idx < cnt) ? bucket_w [e * N_TOKENS + idx] : 0.0f;
    }
    __syncthreads();

    // --- staging geometry: wave wv owns rows [wv*32, wv*32+32) of each tile ---
    const int l4 = lane >> 2;                 // 0..15
    const int kq = lane & 3;                  // 8-bf16 quad
    const int rA = wv * 32 + l4;
    const int s0 = slt[rA], s1 = slt[rA + 16];
    const int tk0 = (s0 < 0) ? 0 : (s0 >> 1);
    const int tk1 = (s1 < 0) ? 0 : (s1 >> 1);

    const unsigned short* sX0 = xh + (size_t)tk0 * IN_DIM + kq * 8;
    const unsigned short* sX1 = xh + (size_t)tk1 * IN_DIM + kq * 8;
    const unsigned short* sW0 = wh + ((size_t)e * OUT_DIM + ot * BM + rA) * IN_DIM + kq * 8;
    const unsigned short* sW1 = sW0 + (size_t)16 * IN_DIM;

    unsigned short* dX = &Xh[wv * 1024];      // 2KB chunk per wave
    unsigned short* dW = &Wh[wv * 1024];

    // --- compute geometry ---
    const int wm = wv >> 1, wn = wv & 1;
    const int fr = lane & 15;                 // frag row/col
    const int kb = (lane >> 4) * 8;           // frag k base (ushort)

    f32x4 acc[4][4];
#pragma unroll
    for (int mi = 0; mi < 4; ++mi)
#pragma unroll
        for (int ni = 0; ni < 4; ++ni) acc[mi][ni] = (f32x4)0.0f;

    for (int k0 = 0; k0 < IN_DIM; k0 += KS) {
        __syncthreads();                      // everyone done reading prev tile
        gl16(sX0 + k0, dX);  gl16(sX1 + k0, dX + 512);
        gl16(sW0 + k0, dW);  gl16(sW1 + k0, dW + 512);
        __syncthreads();                      // vmcnt drained -> tile ready

        bf16x8 ah[4], bh[4];
#pragma unroll
        for (int mi = 0; mi < 4; ++mi)
            ah[mi] = *(const bf16x8*)&Xh[(wm * 64 + mi * 16 + fr) * KS + kb];
#pragma unroll
        for (int ni = 0; ni < 4; ++ni)
            bh[ni] = *(const bf16x8*)&Wh[(wn * 64 + ni * 16 + fr) * KS + kb];
#pragma unroll
        for (int mi = 0; mi < 4; ++mi)
#pragma unroll
            for (int ni = 0; ni < 4; ++ni)
                acc[mi][ni] = __builtin_amdgcn_mfma_f32_16x16x32_bf16(ah[mi], bh[ni], acc[mi][ni], 0, 0, 0);
    }

    // --- epilogue: tmp[slot] = w * (acc + bias); C/D: col=lane&15, row=(lane>>4)*4+r ---
    const int colbase = ot * BM + wn * 64;
    float bias[4];
#pragma unroll
    for (int ni = 0; ni < 4; ++ni) bias[ni] = be[(size_t)e * OUT_DIM + colbase + ni * 16 + fr];

#pragma unroll
    for (int mi = 0; mi < 4; ++mi) {
#pragma unroll
        for (int r = 0; r < 4; ++r) {
            const int ri = wm * 64 + mi * 16 + (lane >> 4) * 4 + r;
            const int s  = slt[ri];
            if (s < 0) continue;
            const float w = wts[ri];
            float* orow = tmp + (size_t)s * OUT_DIM + colbase;
#pragma unroll
            for (int ni = 0; ni < 4; ++ni)
                orow[ni * 16 + fr] = w * (acc[mi][ni][r] + bias[ni]);
        }
    }
}

// =================== combine: out[t] = tmp[2t] + tmp[2t+1] ===================
__global__ __launch_bounds__(256) void combine_kernel(
    const float* __restrict__ tmp, float* __restrict__ out, int n4)
{
    int i = blockIdx.x * 256 + threadIdx.x;
    const int stride = gridDim.x * 256;
    const int row4 = OUT_DIM / 4;             // 256 float4 per row
    for (; i < n4; i += stride) {
        int t  = i / row4;
        int d4 = i - t * row4;
        float4 a = ((const float4*)tmp)[(size_t)(2 * t)     * row4 + d4];
        float4 b = ((const float4*)tmp)[(size_t)(2 * t + 1) * row4 + d4];
        float4 o;
        o.x = a.x + b.x; o.y = a.y + b.y; o.z = a.z + b.z; o.w = a.w + b.w;
        ((float4*)out)[i] = o;
    }
}

// =================== launch ===================
extern "C" void kernel_launch(void* const* d_in, const int* in_sizes, int n_in,
                              void* d_out, int out_size, void* d_ws, size_t ws_size,
                              hipStream_t stream) {
    const float* x   = (const float*)d_in[0];
    const float* We  = (const float*)d_in[1];
    const float* be  = (const float*)d_in[2];
    const float* Wg1 = (const float*)d_in[3];
    const float* bg1 = (const float*)d_in[4];
    const float* Wg2 = (const float*)d_in[5];
    const float* bg2 = (const float*)d_in[6];

    float* out     = (float*)d_out;
    float* out_gw  = out + (size_t)N_TOKENS * OUT_DIM;     // [N, 8]
    float* out_idx = out_gw + (size_t)N_TOKENS * NE;       // [N, 2] as float

    char* ws = (char*)d_ws;
    int*   counts = (int*)ws;                              // 8 counters, stride 16 ints
    int*   btok   = (int*)(ws + 1024);                     // 256 KB
    float* bw     = (float*)(ws + 1024 + 262144);          // 256 KB
    unsigned short* xh = (unsigned short*)(ws + 525312);   // 16 MB
    unsigned short* wh = xh + (size_t)N_TOKENS * IN_DIM;   // 16 MB
    float* tmp = (float*)(wh + (size_t)NE * OUT_DIM * IN_DIM);  // 64 MB

    hipMemsetAsync(counts, 0, 1024, stream);

    conv_bf16<<<1024, 256, 0, stream>>>(x,  xh, (N_TOKENS * IN_DIM) / 4);
    conv_bf16<<<1024, 256, 0, stream>>>(We, wh, (NE * OUT_DIM * IN_DIM) / 4);

    gating_kernel<<<N_TOKENS / 64, 256, 0, stream>>>(
        x, Wg1, bg1, Wg2, bg2, out_gw, out_idx, counts, btok, bw);

    dim3 grid(OUT_DIM / BM, N_TOKENS / BM, NE);
    expert_gemm<<<grid, 256, 0, stream>>>(xh, wh, be, counts, btok, bw, tmp);

    combine_kernel<<<2048, 256, 0, stream>>>(tmp, out, (N_TOKENS * OUT_DIM) / 4);
}

// Round 7
// 237.095 us; speedup vs baseline: 4.1266x; 1.0906x over previous
//
#include <hip/hip_runtime.h>
#include <stdint.h>

#define N_TOKENS 8192
#define IN_DIM   1024
#define OUT_DIM  1024
#define NE       8
#define HID      64

typedef __attribute__((ext_vector_type(8))) short bf16x8;   // 8 bf16 = 4 VGPR
typedef __attribute__((ext_vector_type(4))) float f32x4;

// ---------------- helpers ----------------
__device__ __forceinline__ unsigned short f2bf(float f) {   // RN-even fp32->bf16
    unsigned int b = __float_as_uint(f);
    b += 0x7fffu + ((b >> 16) & 1u);
    return (unsigned short)(b >> 16);
}
__device__ __forceinline__ float bf2f(unsigned short u) {
    return __uint_as_float(((unsigned int)u) << 16);
}

__device__ __forceinline__ void gl16(const unsigned short* g, unsigned short* l) {
    // async global->LDS, 16B per lane; LDS dest = wave-uniform base + lane*16
    __builtin_amdgcn_global_load_lds(
        (const __attribute__((address_space(1))) unsigned int*)g,
        (__attribute__((address_space(3))) unsigned int*)l,
        16, 0, 0);
}

// =================== fp32 -> bf16 (hi only) ===================
__global__ __launch_bounds__(256) void conv_bf16(
    const float* __restrict__ src, unsigned short* __restrict__ dst, int n4)
{
    int i = blockIdx.x * 256 + threadIdx.x;
    const int stride = gridDim.x * 256;
    for (; i < n4; i += stride) {
        float4 v = ((const float4*)src)[i];
        ushort4 h;
        h.x = f2bf(v.x); h.y = f2bf(v.y); h.z = f2bf(v.z); h.w = f2bf(v.w);
        ((ushort4*)dst)[i] = h;
    }
}

// =================== fp32 -> bf16 hi/lo split (Wg1, 64K elems) ===================
__global__ __launch_bounds__(256) void split_wg1(
    const float* __restrict__ src, unsigned short* __restrict__ hi,
    unsigned short* __restrict__ lo, int n4)
{
    int i = blockIdx.x * 256 + threadIdx.x;
    if (i >= n4) return;
    float4 v = ((const float4*)src)[i];
    ushort4 h, l;
    h.x = f2bf(v.x); l.x = f2bf(v.x - bf2f(h.x));
    h.y = f2bf(v.y); l.y = f2bf(v.y - bf2f(h.y));
    h.z = f2bf(v.z); l.z = f2bf(v.z - bf2f(h.z));
    h.w = f2bf(v.w); l.w = f2bf(v.w - bf2f(h.w));
    ((ushort4*)hi)[i] = h;
    ((ushort4*)lo)[i] = l;
}

// =================== gating (split-2 bf16 MFMA) ===================
// 64 tokens/block, 128 blocks, 4 waves. H = relu(X*Wg1^T + b) via
// xh*wh + xh*wl + xl*wh (rel err ~2^-18). Also emits xh to global for the
// expert GEMM (fuses the x conversion pass). Scores/softmax/top2 in fp32.
__global__ __launch_bounds__(256) void gating_kernel(
    const float* __restrict__ x, unsigned short* __restrict__ xh_out,
    const unsigned short* __restrict__ wg1h, const unsigned short* __restrict__ wg1l,
    const float* __restrict__ bg1,
    const float* __restrict__ Wg2, const float* __restrict__ bg2,
    float* __restrict__ out_gw, float* __restrict__ out_idx,
    int* __restrict__ counts, int* __restrict__ bucket_tok, float* __restrict__ bucket_w)
{
    __shared__ unsigned short Xh_s[64 * 32], Xl_s[64 * 32];   // [tok][k] bf16, 4KB each
    __shared__ unsigned short Gh_s[64 * 32], Gl_s[64 * 32];   // [hid][k]
    __shared__ float Hs[64][68];
    __shared__ float W2s[NE][HID];
    __shared__ float b2s[NE];

    const int tid  = threadIdx.x;
    const int wv   = tid >> 6;
    const int lane = tid & 63;
    const int t0   = blockIdx.x * 64;

    for (int i = tid; i < NE * HID; i += 256) W2s[i >> 6][i & 63] = Wg2[i];
    if (tid < NE) b2s[tid] = bg2[tid];

    // X staging geometry: thread -> (row r, 8-float chunk c)
    const int r = tid >> 2;            // 0..63
    const int c = tid & 3;             // 0..3 (8 floats each)
    const float* xsrc = x + (size_t)(t0 + r) * IN_DIM + c * 8;
    unsigned short* xdst = xh_out + (size_t)(t0 + r) * IN_DIM + c * 8;

    // Wg1 staging: wave wv stages rows [wv*16, wv*16+16), lane l -> row wv*16+(l>>2), kchunk l&3
    const unsigned short* gh_src = wg1h + (size_t)(wv * 16 + (lane >> 2)) * IN_DIM + (lane & 3) * 8;
    const unsigned short* gl_src = wg1l + (size_t)(wv * 16 + (lane >> 2)) * IN_DIM + (lane & 3) * 8;
    unsigned short* gh_dst = &Gh_s[wv * 512];
    unsigned short* gl_dst = &Gl_s[wv * 512];

    // compute geometry: wave wv owns hid cols [wv*16, wv*16+16)
    const int fr = lane & 15;
    const int kb = (lane >> 4) * 8;

    f32x4 acc[4];
#pragma unroll
    for (int mi = 0; mi < 4; ++mi) acc[mi] = (f32x4)0.0f;

    for (int k0 = 0; k0 < IN_DIM; k0 += 32) {
        // load 32B of x, split to bf16 hi/lo
        float4 v0 = *(const float4*)(xsrc + k0);
        float4 v1 = *(const float4*)(xsrc + k0 + 4);
        bf16x8 xh8, xl8;
        {
            float vv[8] = {v0.x, v0.y, v0.z, v0.w, v1.x, v1.y, v1.z, v1.w};
#pragma unroll
            for (int j = 0; j < 8; ++j) {
                unsigned short h = f2bf(vv[j]);
                xh8[j] = (short)h;
                xl8[j] = (short)f2bf(vv[j] - bf2f(h));
            }
        }
        *(bf16x8*)(xdst + k0) = xh8;                    // feed expert GEMM

        __syncthreads();                                 // prev tile reads done
        *(bf16x8*)&Xh_s[r * 32 + c * 8] = xh8;
        *(bf16x8*)&Xl_s[r * 32 + c * 8] = xl8;
        gl16(gh_src + k0, gh_dst);
        gl16(gl_src + k0, gl_dst);
        __syncthreads();                                 // lds + vmcnt drained

        bf16x8 bh = *(const bf16x8*)&Gh_s[(wv * 16 + fr) * 32 + kb];
        bf16x8 bl = *(const bf16x8*)&Gl_s[(wv * 16 + fr) * 32 + kb];
#pragma unroll
        for (int mi = 0; mi < 4; ++mi) {
            bf16x8 ah = *(const bf16x8*)&Xh_s[(mi * 16 + fr) * 32 + kb];
            bf16x8 al = *(const bf16x8*)&Xl_s[(mi * 16 + fr) * 32 + kb];
            acc[mi] = __builtin_amdgcn_mfma_f32_16x16x32_bf16(ah, bh, acc[mi], 0, 0, 0);
            acc[mi] = __builtin_amdgcn_mfma_f32_16x16x32_bf16(ah, bl, acc[mi], 0, 0, 0);
            acc[mi] = __builtin_amdgcn_mfma_f32_16x16x32_bf16(al, bh, acc[mi], 0, 0, 0);
        }
    }

    // H epilogue: C/D col=lane&15 (hid), row=(lane>>4)*4+reg (+mi*16) (token)
    const float bgv = bg1[wv * 16 + fr];
#pragma unroll
    for (int mi = 0; mi < 4; ++mi)
#pragma unroll
        for (int rg = 0; rg < 4; ++rg)
            Hs[mi * 16 + (lane >> 4) * 4 + rg][wv * 16 + fr] = fmaxf(acc[mi][rg] + bgv, 0.0f);
    __syncthreads();

    if (tid < 64) {                  // wave 0: scores, softmax, top2, scatter
        const int token = t0 + tid;
        float sc[NE];
#pragma unroll
        for (int e2 = 0; e2 < NE; ++e2) {
            float s = b2s[e2];
#pragma unroll
            for (int j = 0; j < HID; ++j) s += Hs[tid][j] * W2s[e2][j];
            sc[e2] = s;
        }
        float m = sc[0];
#pragma unroll
        for (int e2 = 1; e2 < NE; ++e2) m = fmaxf(m, sc[e2]);
        float sum = 0.0f;
#pragma unroll
        for (int e2 = 0; e2 < NE; ++e2) { sc[e2] = expf(sc[e2] - m); sum += sc[e2]; }
        const float inv = 1.0f / sum;
#pragma unroll
        for (int e2 = 0; e2 < NE; ++e2) { sc[e2] *= inv; out_gw[(size_t)token * NE + e2] = sc[e2]; }

        int i1 = 0; float v1 = sc[0];
#pragma unroll
        for (int e2 = 1; e2 < NE; ++e2) if (sc[e2] > v1) { v1 = sc[e2]; i1 = e2; }
        int i2 = -1; float v2 = -1e30f;
#pragma unroll
        for (int e2 = 0; e2 < NE; ++e2) {
            if (e2 == i1) continue;
            if (i2 < 0 || sc[e2] > v2) { v2 = sc[e2]; i2 = e2; }
        }
        out_idx[(size_t)token * 2 + 0] = (float)i1;
        out_idx[(size_t)token * 2 + 1] = (float)i2;

        const unsigned long long lmask = (1ull << tid) - 1ull;
#pragma unroll
        for (int e2 = 0; e2 < NE; ++e2) {
            unsigned long long m1 = __ballot(i1 == e2);
            unsigned long long m2 = __ballot(i2 == e2);
            int c1 = __popcll(m1), c2 = __popcll(m2);
            int base = 0;
            if (tid == 0 && (c1 + c2) > 0) base = atomicAdd(&counts[e2 * 16], c1 + c2);
            base = __shfl(base, 0);
            if (i1 == e2) {
                int pos = base + __popcll(m1 & lmask);
                bucket_tok[e2 * N_TOKENS + pos] = token * 2 + 0;
                bucket_w  [e2 * N_TOKENS + pos] = v1;
            }
            if (i2 == e2) {
                int pos = base + c1 + __popcll(m2 & lmask);
                bucket_tok[e2 * N_TOKENS + pos] = token * 2 + 1;
                bucket_w  [e2 * N_TOKENS + pos] = v2;
            }
        }
    }
}

// =================== grouped expert GEMM (bf16 MFMA) ===================
#define BM 128
#define KS 32

__global__ __launch_bounds__(256) void expert_gemm(
    const unsigned short* __restrict__ xh, const unsigned short* __restrict__ wh,
    const float* __restrict__ be, const int* __restrict__ counts,
    const int* __restrict__ bucket_tok, const float* __restrict__ bucket_w,
    float* __restrict__ tmp)
{
    const int e  = blockIdx.z;
    const int tt = blockIdx.y;
    const int ot = blockIdx.x;
    const int cnt = counts[e * 16];
    if (tt * BM >= cnt) return;

    __shared__ unsigned short Xh[BM * KS], Wh[BM * KS];   // 8KB each
    __shared__ int   slt[BM];
    __shared__ float wts[BM];

    const int tid  = threadIdx.x;
    const int wv   = tid >> 6;
    const int lane = tid & 63;

    if (tid < BM) {
        int idx = tt * BM + tid;
        slt[tid] = (idx < cnt) ? bucket_tok[e * N_TOKENS + idx] : -1;
        wts[tid] = (idx < cnt) ? bucket_w [e * N_TOKENS + idx] : 0.0f;
    }
    __syncthreads();

    const int l4 = lane >> 2;
    const int kq = lane & 3;
    const int rA = wv * 32 + l4;
    const int s0 = slt[rA], s1 = slt[rA + 16];
    const int tk0 = (s0 < 0) ? 0 : (s0 >> 1);
    const int tk1 = (s1 < 0) ? 0 : (s1 >> 1);

    const unsigned short* sX0 = xh + (size_t)tk0 * IN_DIM + kq * 8;
    const unsigned short* sX1 = xh + (size_t)tk1 * IN_DIM + kq * 8;
    const unsigned short* sW0 = wh + ((size_t)e * OUT_DIM + ot * BM + rA) * IN_DIM + kq * 8;
    const unsigned short* sW1 = sW0 + (size_t)16 * IN_DIM;

    unsigned short* dX = &Xh[wv * 1024];
    unsigned short* dW = &Wh[wv * 1024];

    const int wm = wv >> 1, wn = wv & 1;
    const int fr = lane & 15;
    const int kb = (lane >> 4) * 8;

    f32x4 acc[4][4];
#pragma unroll
    for (int mi = 0; mi < 4; ++mi)
#pragma unroll
        for (int ni = 0; ni < 4; ++ni) acc[mi][ni] = (f32x4)0.0f;

    for (int k0 = 0; k0 < IN_DIM; k0 += KS) {
        __syncthreads();
        gl16(sX0 + k0, dX);  gl16(sX1 + k0, dX + 512);
        gl16(sW0 + k0, dW);  gl16(sW1 + k0, dW + 512);
        __syncthreads();

        bf16x8 ah[4], bh[4];
#pragma unroll
        for (int mi = 0; mi < 4; ++mi)
            ah[mi] = *(const bf16x8*)&Xh[(wm * 64 + mi * 16 + fr) * KS + kb];
#pragma unroll
        for (int ni = 0; ni < 4; ++ni)
            bh[ni] = *(const bf16x8*)&Wh[(wn * 64 + ni * 16 + fr) * KS + kb];
#pragma unroll
        for (int mi = 0; mi < 4; ++mi)
#pragma unroll
            for (int ni = 0; ni < 4; ++ni)
                acc[mi][ni] = __builtin_amdgcn_mfma_f32_16x16x32_bf16(ah[mi], bh[ni], acc[mi][ni], 0, 0, 0);
    }

    const int colbase = ot * BM + wn * 64;
    float bias[4];
#pragma unroll
    for (int ni = 0; ni < 4; ++ni) bias[ni] = be[(size_t)e * OUT_DIM + colbase + ni * 16 + fr];

#pragma unroll
    for (int mi = 0; mi < 4; ++mi) {
#pragma unroll
        for (int r = 0; r < 4; ++r) {
            const int ri = wm * 64 + mi * 16 + (lane >> 4) * 4 + r;
            const int s  = slt[ri];
            if (s < 0) continue;
            const float w = wts[ri];
            float* orow = tmp + (size_t)s * OUT_DIM + colbase;
#pragma unroll
            for (int ni = 0; ni < 4; ++ni)
                orow[ni * 16 + fr] = w * (acc[mi][ni][r] + bias[ni]);
        }
    }
}

// =================== combine: out[t] = tmp[2t] + tmp[2t+1] ===================
__global__ __launch_bounds__(256) void combine_kernel(
    const float* __restrict__ tmp, float* __restrict__ out, int n4)
{
    int i = blockIdx.x * 256 + threadIdx.x;
    const int stride = gridDim.x * 256;
    const int row4 = OUT_DIM / 4;
    for (; i < n4; i += stride) {
        int t  = i / row4;
        int d4 = i - t * row4;
        float4 a = ((const float4*)tmp)[(size_t)(2 * t)     * row4 + d4];
        float4 b = ((const float4*)tmp)[(size_t)(2 * t + 1) * row4 + d4];
        float4 o;
        o.x = a.x + b.x; o.y = a.y + b.y; o.z = a.z + b.z; o.w = a.w + b.w;
        ((float4*)out)[i] = o;
    }
}

// =================== launch ===================
extern "C" void kernel_launch(void* const* d_in, const int* in_sizes, int n_in,
                              void* d_out, int out_size, void* d_ws, size_t ws_size,
                              hipStream_t stream) {
    const float* x   = (const float*)d_in[0];
    const float* We  = (const float*)d_in[1];
    const float* be  = (const float*)d_in[2];
    const float* Wg1 = (const float*)d_in[3];
    const float* bg1 = (const float*)d_in[4];
    const float* Wg2 = (const float*)d_in[5];
    const float* bg2 = (const float*)d_in[6];

    float* out     = (float*)d_out;
    float* out_gw  = out + (size_t)N_TOKENS * OUT_DIM;     // [N, 8]
    float* out_idx = out_gw + (size_t)N_TOKENS * NE;       // [N, 2] as float

    char* ws = (char*)d_ws;
    int*   counts = (int*)ws;                               // stride-16 counters
    int*   btok   = (int*)(ws + 1024);
    float* bw     = (float*)(ws + 1024 + 262144);
    unsigned short* xh   = (unsigned short*)(ws + 525312);           // 16 MB
    unsigned short* wh   = xh + (size_t)N_TOKENS * IN_DIM;           // 16 MB
    unsigned short* wg1h = wh + (size_t)NE * OUT_DIM * IN_DIM;       // 128 KB
    unsigned short* wg1l = wg1h + (size_t)HID * IN_DIM;              // 128 KB
    float* tmp = (float*)(wg1l + (size_t)HID * IN_DIM);              // 64 MB

    hipMemsetAsync(counts, 0, 1024, stream);

    split_wg1<<<64, 256, 0, stream>>>(Wg1, wg1h, wg1l, (HID * IN_DIM) / 4);
    conv_bf16<<<1024, 256, 0, stream>>>(We, wh, (NE * OUT_DIM * IN_DIM) / 4);

    gating_kernel<<<N_TOKENS / 64, 256, 0, stream>>>(
        x, xh, wg1h, wg1l, bg1, Wg2, bg2, out_gw, out_idx, counts, btok, bw);

    dim3 grid(OUT_DIM / BM, N_TOKENS / BM, NE);
    expert_gemm<<<grid, 256, 0, stream>>>(xh, wh, be, counts, btok, bw, tmp);

    combine_kernel<<<2048, 256, 0, stream>>>(tmp, out, (N_TOKENS * OUT_DIM) / 4);
}